// Round 11
// baseline (765.536 us; speedup 1.0000x reference)
//
#include <hip/hip_runtime.h>
#include <math.h>

#define N_NODES 50000
#define N_EDGES 800000
#define F 128         // H*C
#define H 4
#define C 32
#define ED 16
#define L 3
#define NEG 0.2f
#define ET (N_EDGES + N_NODES)   // edges incl. self-loops
#define SCAN_B ((N_NODES + 255) / 256)   // 196 blocks for phase-A scan
#define POOL_B 1024               // phase-A pool blocks

typedef unsigned short bf16_t;

__device__ __forceinline__ bf16_t f2bf(float f) {   // round-to-nearest-even
    unsigned u = __float_as_uint(f);
    unsigned r = (u + 0x7fffu + ((u >> 16) & 1u)) >> 16;
    return (bf16_t)r;
}
__device__ __forceinline__ float bf2f(bf16_t b) {
    return __uint_as_float(((unsigned)b) << 16);
}

// ---------------- CSR build ----------------

__global__ void k_count(const int* __restrict__ dst, int* __restrict__ deg) {
    int e = blockIdx.x * 256 + threadIdx.x;
    if (e < N_EDGES) atomicAdd(&deg[dst[e]], 1);
}

// 3-phase exclusive scan of (deg[i]+1):
__global__ __launch_bounds__(256) void k_scanA(const int* __restrict__ deg,
                                               int* __restrict__ off, int* __restrict__ bsum) {
    __shared__ int sh[256];
    int t = threadIdx.x;
    int i = blockIdx.x * 256 + t;
    int v = (i < N_NODES) ? (deg[i] + 1) : 0;
    sh[t] = v;
    __syncthreads();
    #pragma unroll
    for (int d = 1; d < 256; d <<= 1) {
        int u = (t >= d) ? sh[t - d] : 0;
        __syncthreads();
        sh[t] += u;
        __syncthreads();
    }
    if (i < N_NODES) off[i] = sh[t] - v;      // exclusive
    if (t == 255) bsum[blockIdx.x] = sh[255];
}

__global__ __launch_bounds__(256) void k_scanB(const int* __restrict__ bsum,
                                               int* __restrict__ boff, int* __restrict__ off) {
    __shared__ int sh[256];
    int t = threadIdx.x;
    int v = (t < SCAN_B) ? bsum[t] : 0;
    sh[t] = v;
    __syncthreads();
    #pragma unroll
    for (int d = 1; d < 256; d <<= 1) {
        int u = (t >= d) ? sh[t - d] : 0;
        __syncthreads();
        sh[t] += u;
        __syncthreads();
    }
    if (t < SCAN_B) boff[t] = sh[t] - v;      // exclusive
    if (t == 255) off[N_NODES] = sh[255];     // grand total (== ET)
}

__global__ void k_scanC(int* __restrict__ off, const int* __restrict__ boff) {
    int i = blockIdx.x * 256 + threadIdx.x;
    if (i < N_NODES) off[i] += boff[blockIdx.x];
}

// packed scatter: one 8B store per edge -> half the scattered dirty lines.
// se_csr[slot] = {src, eid}; eid >= N_EDGES marks the self-loop slot.
__global__ void k_scatter(const int* __restrict__ ei, const int* __restrict__ off,
                          int* __restrict__ cursor, int2* __restrict__ se_csr) {
    int e = blockIdx.x * 256 + threadIdx.x;
    if (e < N_EDGES) {
        int d = ei[N_EDGES + e];
        int p = atomicAdd(&cursor[d], 1);
        se_csr[off[d] + p] = make_int2(ei[e], e);
    } else if (e < ET) {
        int nn = e - N_EDGES;
        int p = atomicAdd(&cursor[nn], 1);
        se_csr[off[nn] + p] = make_int2(nn, e);
    }
}

// we2[l][d][h] = sum_c W_edge[l][d, h*C+c] * att_edge[l][h][c]
__global__ void k_we2(const float* __restrict__ W_edge, const float* __restrict__ att_edge,
                      float* __restrict__ we2) {
    int idx = blockIdx.x * 64 + threadIdx.x;
    if (idx >= L * ED * H) return;
    int l = idx / (ED * H);
    int r = idx % (ED * H);
    int d = r / H, h = r % H;
    float s = 0.f;
    for (int c = 0; c < C; c++)
        s += W_edge[(size_t)(l * ED + d) * (H * C) + h * C + c] * att_edge[(l * H + h) * C + c];
    we2[idx] = s;
}

// ---------------- per-layer ----------------

// GEMM with fused a_s/a_d epilogue; writes hp in bf16 (consumed only by gathers).
#define BM 64
#define BK 32
__global__ __launch_bounds__(256) void k_gemm(const float* __restrict__ A,
                                              const float* __restrict__ W,
                                              const float* __restrict__ att_src_l,
                                              const float* __restrict__ att_dst_l,
                                              bf16_t* __restrict__ hpb,
                                              float* __restrict__ a_s,
                                              float* __restrict__ a_d) {
    __shared__ float As[BM][BK + 1];
    __shared__ float Bs[BK][F];
    int block_row = blockIdx.x * BM;
    int t = threadIdx.x;
    int tx = t & 31;   // col group (channel within head)
    int ty = t >> 5;   // row group (0..7)
    float acc[8][4] = {};
    for (int k0 = 0; k0 < F; k0 += BK) {
        #pragma unroll
        for (int i = 0; i < 2; i++) {            // A tile: 64x32 = 512 float4
            int idx = t + i * 256;
            int r = idx >> 3, cq = idx & 7;
            int gr = block_row + r;
            float4 v = make_float4(0.f, 0.f, 0.f, 0.f);
            if (gr < N_NODES) v = *(const float4*)&A[(size_t)gr * F + k0 + cq * 4];
            As[r][cq * 4 + 0] = v.x; As[r][cq * 4 + 1] = v.y;
            As[r][cq * 4 + 2] = v.z; As[r][cq * 4 + 3] = v.w;
        }
        #pragma unroll
        for (int i = 0; i < 4; i++) {            // B tile: 32x128 = 1024 float4
            int idx = t + i * 256;
            int r = idx >> 5, cq = idx & 31;
            float4 v = *(const float4*)&W[(size_t)(k0 + r) * F + cq * 4];
            *(float4*)&Bs[r][cq * 4] = v;
        }
        __syncthreads();
        for (int kk = 0; kk < BK; kk++) {
            float b[4];
            #pragma unroll
            for (int j = 0; j < 4; j++) b[j] = Bs[kk][tx + 32 * j];
            #pragma unroll
            for (int i = 0; i < 8; i++) {
                float a = As[ty * 8 + i][kk];
                #pragma unroll
                for (int j = 0; j < 4; j++) acc[i][j] += a * b[j];
            }
        }
        __syncthreads();
    }
    float avs[4], avd[4];
    #pragma unroll
    for (int j = 0; j < 4; j++) {
        avs[j] = att_src_l[j * 32 + tx];
        avd[j] = att_dst_l[j * 32 + tx];
    }
    #pragma unroll
    for (int i = 0; i < 8; i++) {
        int gr = block_row + ty * 8 + i;
        bool ok = (gr < N_NODES);
        if (ok) {
            #pragma unroll
            for (int j = 0; j < 4; j++) hpb[(size_t)gr * F + tx + 32 * j] = f2bf(acc[i][j]);
        }
        #pragma unroll
        for (int j = 0; j < 4; j++) {
            float vs = acc[i][j] * avs[j];
            float vd = acc[i][j] * avd[j];
            #pragma unroll
            for (int m = 1; m < 32; m <<= 1) {   // masks <32 stay within 32-lane half-wave
                vs += __shfl_xor(vs, m, 64);
                vd += __shfl_xor(vd, m, 64);
            }
            if (tx == 0 && ok) {
                a_s[gr * H + j] = vs;
                a_d[gr * H + j] = vd;
            }
        }
    }
}

// Fused alpha+softmax+aggregate: one 64-lane wave per node.
// Lane (k=lane&15, h=lane>>4) holds we2[k][h]; per edge: load edge_attr[eid][k]
// (one 64B line), p = v*we2, shfl_xor{1,2,4,8} reduces over k within each h group
// -> a_e[h] in every lane. alpha = a_s[src][h]+a_d[n][h]+a_e, leaky, exp; then
// bf16 hp gather (2 channels/lane) accumulates. Self-loop term deferred to
// post-loop (exact: softmax normalizes at the end; its a_e = sum(a_e)/deg and
// sae accumulates for free since all lanes see every real edge).
// No max subtraction (|alpha|~6 bounded, fp32-safe).
__global__ __launch_bounds__(256) void k_fagg(const int2* __restrict__ se_csr,
                                              const int* __restrict__ off,
                                              const float* __restrict__ edge_attr,
                                              const float* __restrict__ we2l,
                                              const float* __restrict__ a_s,
                                              const float* __restrict__ a_d,
                                              const bf16_t* __restrict__ hpb,
                                              const float* __restrict__ bias_l,
                                              float* __restrict__ hout) {
    int n = blockIdx.x * 4 + (threadIdx.x >> 6);
    if (n >= N_NODES) return;
    int lane = threadIdx.x & 63;
    int k = lane & 15, h = lane >> 4;
    float myw = we2l[k * H + h];
    int beg = off[n], end = off[n + 1];
    float adn = a_d[(size_t)n * H + h];
    float accA = 0.f, accB = 0.f, den = 0.f, sae = 0.f;
    for (int i = beg; i < end; i++) {
        int2 se = se_csr[i];
        if (se.y < N_EDGES) {
            float v = edge_attr[(size_t)se.y * ED + k];
            float p = v * myw;
            p += __shfl_xor(p, 1, 64);
            p += __shfl_xor(p, 2, 64);
            p += __shfl_xor(p, 4, 64);
            p += __shfl_xor(p, 8, 64);     // a_e[h] in every lane of group h
            sae += p;
            float al = a_s[(size_t)se.x * H + h] + adn + p;
            al = (al > 0.f) ? al : NEG * al;
            float e = __expf(al);
            ushort2 v2 = *(const ushort2*)&hpb[(size_t)se.x * F + 2 * lane];
            accA += e * bf2f(v2.x);
            accB += e * bf2f(v2.y);
            den += e;
        }
    }
    // self-loop: a_e = mean of incoming real-edge a_e (deg = end-beg-1)
    float inv = 1.f / fmaxf((float)(end - beg - 1), 1.f);
    float al = a_s[(size_t)n * H + h] + adn + sae * inv;
    al = (al > 0.f) ? al : NEG * al;
    float e = __expf(al);
    ushort2 v2 = *(const ushort2*)&hpb[(size_t)n * F + 2 * lane];
    accA += e * bf2f(v2.x);
    accB += e * bf2f(v2.y);
    den += e;
    float2 bia = *(const float2*)&bias_l[2 * lane];
    float2 o;
    o.x = fmaxf(accA / den + bia.x, 0.f);
    o.y = fmaxf(accB / den + bia.y, 0.f);
    *(float2*)&hout[(size_t)n * F + 2 * lane] = o;
}

// ---------------- head ----------------

// two-phase atomic-free mean pool.
__global__ __launch_bounds__(256) void k_poolA(const float* __restrict__ hfinal,
                                               float* __restrict__ partials) {
    int t = threadIdx.x;
    int c = t & 127;
    int half = t >> 7;                 // 0/1
    int b = blockIdx.x;                // 0..POOL_B-1
    float s = 0.f;
    for (int n = b * 2 + half; n < N_NODES; n += 2 * POOL_B)
        s += hfinal[(size_t)n * F + c];
    partials[(size_t)c * (2 * POOL_B) + b * 2 + half] = s;
}

__global__ __launch_bounds__(256) void k_poolB(const float* __restrict__ partials,
                                               float* __restrict__ gsum) {
    __shared__ float red[256];
    int c = blockIdx.x;                // 0..127
    int t = threadIdx.x;
    const float* row = &partials[(size_t)c * (2 * POOL_B)];
    float s = 0.f;
    for (int k = t; k < 2 * POOL_B; k += 256) s += row[k];
    red[t] = s;
    __syncthreads();
    for (int stp = 128; stp > 0; stp >>= 1) {
        if (t < stp) red[t] += red[t + stp];
        __syncthreads();
    }
    if (t == 0) gsum[c] = red[0];
}

__global__ __launch_bounds__(256) void k_mlp(const float* __restrict__ gsum, const float* __restrict__ W1,
                                             const float* __restrict__ b1, const float* __restrict__ W2,
                                             const float* __restrict__ b2, float* __restrict__ out) {
    __shared__ float g[F];
    __shared__ float hid[2 * F];
    __shared__ float red[256];
    int t = threadIdx.x;
    if (t < F) g[t] = gsum[t] * (1.0f / N_NODES);
    __syncthreads();
    float s = b1[t];
    for (int k = 0; k < F; k++) s += g[k] * W1[k * (2 * F) + t];
    hid[t] = fmaxf(s, 0.f);
    __syncthreads();
    for (int i = 0; i < 2; i++) {
        red[t] = hid[t] * W2[t * 2 + i];
        __syncthreads();
        for (int stp = 128; stp > 0; stp >>= 1) {
            if (t < stp) red[t] += red[t + stp];
            __syncthreads();
        }
        if (t == 0) out[i] = red[0] + b2[i];
        __syncthreads();
    }
}

// ---------------- launch ----------------

extern "C" void kernel_launch(void* const* d_in, const int* in_sizes, int n_in,
                              void* d_out, int out_size, void* d_ws, size_t ws_size,
                              hipStream_t stream) {
    const float* x        = (const float*)d_in[0];
    const int*   ei       = (const int*)d_in[1];
    const float* edge_attr= (const float*)d_in[2];
    const float* W_src    = (const float*)d_in[3];
    const float* att_src  = (const float*)d_in[4];
    const float* att_dst  = (const float*)d_in[5];
    const float* W_edge   = (const float*)d_in[6];
    const float* att_edge = (const float*)d_in[7];
    const float* bias     = (const float*)d_in[8];
    const float* W1       = (const float*)d_in[9];
    const float* b1       = (const float*)d_in[10];
    const float* W2       = (const float*)d_in[11];
    const float* b2       = (const float*)d_in[12];
    float* out = (float*)d_out;

    char* p = (char*)d_ws;
    auto alloc = [&](size_t bytes) -> char* {
        char* r = p;
        p += (bytes + 255) & ~(size_t)255;
        return r;
    };
    int*      deg      = (int*)alloc((size_t)N_NODES * 4);
    int*      cursor   = (int*)alloc((size_t)N_NODES * 4);
    int*      off      = (int*)alloc((size_t)(N_NODES + 1) * 4);
    int*      bsum     = (int*)alloc((size_t)SCAN_B * 4);
    int*      boff     = (int*)alloc((size_t)SCAN_B * 4);
    int2*     se_csr   = (int2*)alloc((size_t)ET * 8);
    float*    we2      = (float*)alloc((size_t)L * ED * H * 4);
    float*    a_s      = (float*)alloc((size_t)N_NODES * H * 4);
    float*    a_d      = (float*)alloc((size_t)N_NODES * H * 4);
    bf16_t*   hpb      = (bf16_t*)alloc((size_t)N_NODES * F * 2);
    float*    hA       = (float*)alloc((size_t)N_NODES * F * 4);
    float*    hB       = (float*)alloc((size_t)N_NODES * F * 4);
    float*    partials = (float*)alloc((size_t)F * 2 * POOL_B * 4);
    float*    gsum     = (float*)alloc((size_t)F * 4);

    hipMemsetAsync(deg, 0, (size_t)N_NODES * 4, stream);
    hipMemsetAsync(cursor, 0, (size_t)N_NODES * 4, stream);

    const int* dst = ei + N_EDGES;
    k_count<<<(N_EDGES + 255) / 256, 256, 0, stream>>>(dst, deg);
    k_scanA<<<SCAN_B, 256, 0, stream>>>(deg, off, bsum);
    k_scanB<<<1, 256, 0, stream>>>(bsum, boff, off);
    k_scanC<<<SCAN_B, 256, 0, stream>>>(off, boff);
    k_scatter<<<(ET + 255) / 256, 256, 0, stream>>>(ei, off, cursor, se_csr);
    k_we2<<<3, 64, 0, stream>>>(W_edge, att_edge, we2);

    const float* hin = x;
    float* houts[3] = {hA, hB, hA};
    for (int l = 0; l < L; l++) {
        k_gemm<<<(N_NODES + BM - 1) / BM, 256, 0, stream>>>(hin, W_src + (size_t)l * F * F,
                                                            att_src + l * H * C, att_dst + l * H * C,
                                                            hpb, a_s, a_d);
        k_fagg<<<(N_NODES + 3) / 4, 256, 0, stream>>>(se_csr, off, edge_attr,
                                                      we2 + l * ED * H, a_s, a_d,
                                                      hpb, bias + l * F, houts[l]);
        hin = houts[l];
    }
    k_poolA<<<POOL_B, 256, 0, stream>>>(hA, partials);
    k_poolB<<<F, 256, 0, stream>>>(partials, gsum);
    k_mlp<<<1, 256, 0, stream>>>(gsum, W1, b1, W2, b2, out);
}